// Round 5
// baseline (1706.688 us; speedup 1.0000x reference)
//
#include <hip/hip_runtime.h>
#include <stdint.h>

typedef _Float16 f16x8 __attribute__((ext_vector_type(8)));
typedef unsigned short u16x8 __attribute__((ext_vector_type(8)));
typedef float f32x4 __attribute__((ext_vector_type(4)));
typedef unsigned long long u64t;

#define MFMA16(a,b,c) __builtin_amdgcn_mfma_f32_16x16x32_f16((a),(b),(c),0,0,0)

// problem dims
#define LSEQ 256
#define H0N  269   // N_INTER
#define H1N  179   // N_COMMAND
#define H2N  64    // N_MOTOR
#define H0P  272   // padded
#define H1P  192
#define K0REAL 333 // 64 + 269
#define K1REAL 448 // 269 + 179
#define K2REAL 243 // 179 + 64
#define KK0  11    // K0 padded to 352
#define KK1  15    // K1 layout [a:272|h1:192] padded to 480
#define KK2  8     // K2 layout [b:192|c:64] = 256
#define XH0S 360
#define XH1S 488
#define XH2S 264
#define MR   32    // batch rows per group

// rings
#define D0   8
#define D1   8
#define D2   4

// ws layout per group (bytes)
#define H0_OFF   0
#define H0_SLOT  (MR*H0P*2)            // 17408
#define H1_OFF   (D0*H0_SLOT)          // 139264
#define H1_SLOT  (MR*H1P*2)            // 12288
#define C2_OFF   (H1_OFF + D1*H1_SLOT) // 237568
#define C2_SLOT  (MR*64*2)             // 4096
#define CNT_OFF  (C2_OFF + D2*C2_SLOT) // 253952 (64 words used)
#define GSTRIDE  262144                // 256 KiB

#define BIGNEG   (-(1<<28))

__device__ __forceinline__ unsigned short f2h_bits(float v) {
  return __builtin_bit_cast(unsigned short, (_Float16)v);
}

// ---- cache-bypassing (coherence-point) data movement: relaxed agent atomics ----
__device__ __forceinline__ u16x8 ldg16_sc(const unsigned short* p) {
  const u64t* q = (const u64t*)p;
  u64t a = __hip_atomic_load(q,     __ATOMIC_RELAXED, __HIP_MEMORY_SCOPE_AGENT);
  u64t b = __hip_atomic_load(q + 1, __ATOMIC_RELAXED, __HIP_MEMORY_SCOPE_AGENT);
  union { u64t d[2]; u16x8 v; } u; u.d[0] = a; u.d[1] = b; return u.v;
}
__device__ __forceinline__ void stg_h_sc(unsigned short* p, unsigned short v) {
  __hip_atomic_store(p, v, __ATOMIC_RELAXED, __HIP_MEMORY_SCOPE_AGENT);
}
__device__ __forceinline__ unsigned int ld_cnt(const unsigned int* p) {
  return __hip_atomic_load(p, __ATOMIC_RELAXED, __HIP_MEMORY_SCOPE_AGENT);
}
// one-RTT parallel poll: lane i watches word i; exit when ALL lanes' conditions hold.
// Conditions are monotonic, so waves may exit at different times safely.
__device__ __forceinline__ void poll_all(const unsigned int* cw, int tgt) {
  for (int it = 0; it < (1 << 17); ++it) {   // bounded: no hang on protocol bug
    int v = (int)ld_cnt(cw);
    if (__all(v >= tgt)) return;
    __builtin_amdgcn_s_sleep(1);
  }
}
// per-wave publish: waits own wave's outstanding stores, then flags progress
__device__ __forceinline__ void publish(unsigned int* w, unsigned int v) {
  asm volatile("s_waitcnt vmcnt(0)" ::: "memory");
  __hip_atomic_store(w, v, __ATOMIC_RELAXED, __HIP_MEMORY_SCOPE_AGENT);
}

// ---------------- init: zero rings+counters, load hidden_state into "t=-1" slots ----------------
__global__ void __launch_bounds__(256) init_state(const float* __restrict__ hs, char* __restrict__ ws) {
  int g = blockIdx.x, tid = threadIdx.x;
  char* gb = ws + (size_t)g * GSTRIDE;
  uint4 z4 = {0,0,0,0};
  for (int i = tid; i < (CNT_OFF + 256) / 16; i += 256) ((uint4*)gb)[i] = z4;
  __syncthreads();
  unsigned short* H0 = (unsigned short*)(gb + H0_OFF + (size_t)(D0-1)*H0_SLOT);
  unsigned short* H1 = (unsigned short*)(gb + H1_OFF + (size_t)(D1-1)*H1_SLOT);
  unsigned short* C2 = (unsigned short*)(gb + C2_OFF + (size_t)(D2-1)*C2_SLOT);
  int b0 = g * MR;
  for (int i = tid; i < MR*H0N; i += 256) { int r = i/H0N, c = i%H0N; H0[r*H0P + c] = f2h_bits(hs[(size_t)(b0+r)*512 + c]); }
  for (int i = tid; i < MR*H1N; i += 256) { int r = i/H1N, c = i%H1N; H1[r*H1P + c] = f2h_bits(hs[(size_t)(b0+r)*512 + H0N + c]); }
  for (int i = tid; i < MR*64;  i += 256) { int r = i>>6,  c = i&63;  C2[r*64 + c]  = f2h_bits(hs[(size_t)(b0+r)*512 + 448 + c]); }
}

// ---------------- weight fragment builder (B operand, K x 16 tile) ----------------
template<int KK, int MODE>
__device__ __forceinline__ void build_frag(f16x8* wf, const float* __restrict__ W, const float* __restrict__ Msk,
                                           int h, int Kreal, int gate, int tile, int lane) {
  int col = tile * 16 + (lane & 15);
  bool nv = (col < h);
  #pragma unroll
  for (int kk = 0; kk < KK; ++kk) {
    f16x8 s;
    #pragma unroll
    for (int e = 0; e < 8; ++e) {
      int k = kk*32 + ((lane >> 4) << 3) + e;
      int wc;
      if (MODE == 0)      wc = (k < 333) ? k : -1;                                  // [x64|h269]
      else if (MODE == 1) wc = (k < 269) ? k : ((k >= 272 && k < 451) ? (k - 3) : -1);  // [a272|h1 192]
      else                wc = (k < 179) ? k : ((k >= 192 && k < 256) ? (k - 13) : -1); // [b192|c64]
      float val = 0.f;
      if (nv && wc >= 0) {
        val = W[(size_t)(gate * h + col) * Kreal + wc];
        if (gate < 2) val *= Msk[(size_t)col * Kreal + wc];
      }
      s[e] = (_Float16)val;
    }
    wf[kk] = s;
  }
}

__device__ __forceinline__ f16x8 lda(const unsigned short* xh, int stride, int mt, int kk, int lane) {
  const unsigned short* p = xh + (size_t)(mt*16 + (lane & 15)) * stride + kk*32 + ((lane >> 4) << 3);
  return __builtin_bit_cast(f16x8, *(const u16x8*)p);
}

// ---------------- persistent cascade kernel ----------------
// Per group: 9 WGs. j=0..4 cell0 (tile = j*4+wave, 17 active waves);
// j=5..7 cell1 (tile = (j-5)*4+wave, 12 waves); j=8 cell2+y (tile = wave, 4 waves).
// Progress words (per WAVE, block of 64 u32): P0 = [0..16], P1 = [20..31], P2 = [32..35].
// P[i] = t+1 once that wave's step-t stores are at the coherence point.
// Poll conditions (lane l watches word l, target t+dlt):
//  cell0@t: P0 >= t (a_{t-1} done), P1 >= t-7 (a-ring: readers of a_{t-8} done)
//  cell1@t: P0 >= t+1 (a_t), P1 >= t (b_{t-1}), P2 >= t-7 (b-ring)
//  cell2@t: P1 >= t+1 (b_t); c-ring + y hazards are intra-WG (barrier-ordered)
// Dep graph is acyclic in t -> deadlock-free. One __syncthreads per step
// (stage->MFMA); LDS xh double-buffered so wave skew (<=1 step) is safe.
__global__ void __launch_bounds__(256, 1) rnn_persist(
    const float* __restrict__ dt,
    const float* __restrict__ W0, const float* __restrict__ b0v,
    const float* __restrict__ W1, const float* __restrict__ b1v,
    const float* __restrict__ W2, const float* __restrict__ b2v,
    const float* __restrict__ Wout, const float* __restrict__ boutg,
    const float* __restrict__ M0, const float* __restrict__ M1, const float* __restrict__ M2,
    float* __restrict__ out, char* __restrict__ ws)
{
  __shared__ __attribute__((aligned(16))) unsigned short xh[2][MR * XH1S]; // 2 x 31232 B

  int tid = threadIdx.x;
  int lane = tid & 63, wave = tid >> 6;
  int bid = blockIdx.x;
  int j = bid >> 4;          // role WG index 0..8 (stride-16 bid keeps a group on one XCD)
  int g = bid & 15;          // group 0..15
  int b0 = g * MR;

  char* gb = ws + (size_t)g * GSTRIDE;
  unsigned short* H0r = (unsigned short*)(gb + H0_OFF);
  unsigned short* H1r = (unsigned short*)(gb + H1_OFF);
  unsigned short* C2r = (unsigned short*)(gb + C2_OFF);
  unsigned int*   cnt = (unsigned int*)(gb + CNT_OFF);   // 64 words
  const unsigned int* cw = cnt + lane;

  u16x8 zz = {0,0,0,0,0,0,0,0};

  if (j < 5) {
    // ================= cell0: tile-per-wave, all 4 gates in-wave =================
    int tile = j*4 + wave;
    bool act = (tile < 17);
    int ncol = tile*16 + (lane & 15);
    bool cok = act && (ncol < H0N);
    f16x8 wf[4][KK0];
    if (act) {
      #pragma unroll
      for (int g4 = 0; g4 < 4; ++g4) build_frag<KK0,0>(wf[g4], W0, M0, H0N, K0REAL, g4, tile, lane);
    }
    float bb[4] = {0.f,0.f,0.f,0.f};
    if (cok) {
      for (int g4 = 0; g4 < 4; ++g4) bb[g4] = b0v[g4*H0N + ncol];
    }
    // static k-pad (cols 336..351), both parities
    for (int p = 0; p < 2; ++p)
      for (int idx = tid; idx < MR*2; idx += 256) {
        int r = idx >> 1, c8 = 336 + (idx & 1)*8;
        *(u16x8*)(&xh[p][(size_t)r*XH0S + c8]) = zz;
      }
    __syncthreads();
    int dlt = (lane < 17) ? 0 : (lane >= 20 && lane < 32) ? -7 : BIGNEG;
    for (int t = 0; t < LSEQ; ++t) {
      unsigned short* xb = xh[t & 1];
      { // stage x_t (no cross-WG dep) before polling
        int row = tid >> 3, c = (tid & 7) * 8;
        const float* src = dt + ((size_t)(b0 + row) * LSEQ + t) * 64 + c;
        float4 fa = *(const float4*)src;
        float4 fb = *(const float4*)(src + 4);
        unsigned short* d = xb + (size_t)row * XH0S + c;
        d[0]=f2h_bits(fa.x); d[1]=f2h_bits(fa.y); d[2]=f2h_bits(fa.z); d[3]=f2h_bits(fa.w);
        d[4]=f2h_bits(fb.x); d[5]=f2h_bits(fb.y); d[6]=f2h_bits(fb.z); d[7]=f2h_bits(fb.w);
      }
      poll_all(cw, t + dlt);
      { // stage a_{t-1}
        const unsigned short* H0s = H0r + (size_t)((t + D0 - 1) & (D0 - 1)) * MR * H0P;
        for (int idx = tid; idx < MR*34; idx += 256) {
          int r = idx / 34, c8 = (idx % 34) * 8;
          *(u16x8*)(xb + (size_t)r*XH0S + 64 + c8) = ldg16_sc(H0s + (size_t)r*H0P + c8);
        }
      }
      __syncthreads();
      if (act) {
        f32x4 ac[4][2];
        #pragma unroll
        for (int g4 = 0; g4 < 4; ++g4) { ac[g4][0] = (f32x4){0,0,0,0}; ac[g4][1] = (f32x4){0,0,0,0}; }
        #pragma unroll
        for (int kk = 0; kk < KK0; ++kk) {
          f16x8 a0 = lda(xb, XH0S, 0, kk, lane);
          f16x8 a1 = lda(xb, XH0S, 1, kk, lane);
          #pragma unroll
          for (int g4 = 0; g4 < 4; ++g4) {
            ac[g4][0] = MFMA16(a0, wf[g4][kk], ac[g4][0]);
            ac[g4][1] = MFMA16(a1, wf[g4][kk], ac[g4][1]);
          }
        }
        unsigned short* Hn = H0r + (size_t)(t & (D0 - 1)) * MR * H0P;
        #pragma unroll
        for (int m = 0; m < 2; ++m) {
          #pragma unroll
          for (int r = 0; r < 4; ++r) {
            float ff1 = ac[0][m][r] + bb[0];
            float ff2 = ac[1][m][r] + bb[1];
            float ta  = ac[2][m][r] + bb[2];
            float tb  = ac[3][m][r] + bb[3];
            float ti  = 1.f / (1.f + __expf(-(ta + tb)));
            float hv  = tanhf(ff1)*(1.f - ti) + ti*tanhf(ff2);
            if (cok) stg_h_sc(&Hn[(size_t)(m*16 + (lane>>4)*4 + r)*H0P + ncol], f2h_bits(hv));
          }
        }
        if (lane == 0) publish(&cnt[tile], t + 1);
      }
    }
  } else if (j < 8) {
    // ================= cell1 =================
    int tile = (j - 5)*4 + wave;          // 0..11, all active
    int ncol = tile*16 + (lane & 15);
    bool cok = (ncol < H1N);
    f16x8 wf[4][KK1];
    #pragma unroll
    for (int g4 = 0; g4 < 4; ++g4) build_frag<KK1,1>(wf[g4], W1, M1, H1N, K1REAL, g4, tile, lane);
    float bb[4] = {0.f,0.f,0.f,0.f};
    if (cok) {
      for (int g4 = 0; g4 < 4; ++g4) bb[g4] = b1v[g4*H1N + ncol];
    }
    for (int p = 0; p < 2; ++p)
      for (int idx = tid; idx < MR*2; idx += 256) {   // k-pad 464..479
        int r = idx >> 1, c8 = 464 + (idx & 1)*8;
        *(u16x8*)(&xh[p][(size_t)r*XH1S + c8]) = zz;
      }
    __syncthreads();
    int dlt = (lane < 17) ? 1 : (lane >= 20 && lane < 32) ? 0 : (lane >= 32 && lane < 36) ? -7 : BIGNEG;
    for (int t = 0; t < LSEQ; ++t) {
      unsigned short* xb = xh[t & 1];
      poll_all(cw, t + dlt);
      {
        const unsigned short* As = H0r + (size_t)(t & (D0 - 1)) * MR * H0P;
        const unsigned short* Bs = H1r + (size_t)((t + D1 - 1) & (D1 - 1)) * MR * H1P;
        for (int idx = tid; idx < MR*34; idx += 256) {
          int r = idx/34, c8 = (idx%34)*8;
          *(u16x8*)(xb + (size_t)r*XH1S + c8) = ldg16_sc(As + (size_t)r*H0P + c8);
        }
        for (int idx = tid; idx < MR*24; idx += 256) {
          int r = idx/24, c8 = (idx%24)*8;
          *(u16x8*)(xb + (size_t)r*XH1S + 272 + c8) = ldg16_sc(Bs + (size_t)r*H1P + c8);
        }
      }
      __syncthreads();
      {
        f32x4 ac[4][2];
        #pragma unroll
        for (int g4 = 0; g4 < 4; ++g4) { ac[g4][0] = (f32x4){0,0,0,0}; ac[g4][1] = (f32x4){0,0,0,0}; }
        #pragma unroll
        for (int kk = 0; kk < KK1; ++kk) {
          f16x8 a0 = lda(xb, XH1S, 0, kk, lane);
          f16x8 a1 = lda(xb, XH1S, 1, kk, lane);
          #pragma unroll
          for (int g4 = 0; g4 < 4; ++g4) {
            ac[g4][0] = MFMA16(a0, wf[g4][kk], ac[g4][0]);
            ac[g4][1] = MFMA16(a1, wf[g4][kk], ac[g4][1]);
          }
        }
        unsigned short* Hn = H1r + (size_t)(t & (D1 - 1)) * MR * H1P;
        #pragma unroll
        for (int m = 0; m < 2; ++m) {
          #pragma unroll
          for (int r = 0; r < 4; ++r) {
            float ff1 = ac[0][m][r] + bb[0];
            float ff2 = ac[1][m][r] + bb[1];
            float ta  = ac[2][m][r] + bb[2];
            float tb  = ac[3][m][r] + bb[3];
            float ti  = 1.f / (1.f + __expf(-(ta + tb)));
            float hv  = tanhf(ff1)*(1.f - ti) + ti*tanhf(ff2);
            if (cok) stg_h_sc(&Hn[(size_t)(m*16 + (lane>>4)*4 + r)*H1P + ncol], f2h_bits(hv));
          }
        }
        if (lane == 0) publish(&cnt[20 + tile], t + 1);
      }
    }
  } else {
    // ================= cell2 + y (single WG; ring/y hazards intra-WG) =================
    int tile = wave;                       // 0..3
    int ncol = tile*16 + (lane & 15);      // < 64 always
    f16x8 wf[4][KK2], woutf[2];
    #pragma unroll
    for (int g4 = 0; g4 < 4; ++g4) build_frag<KK2,2>(wf[g4], W2, M2, H2N, K2REAL, g4, tile, lane);
    {
      int wcol = ncol;                     // y-tile = wave
      #pragma unroll
      for (int kk = 0; kk < 2; ++kk) {
        f16x8 s;
        #pragma unroll
        for (int e = 0; e < 8; ++e) {
          int k = kk*32 + ((lane >> 4) << 3) + e;
          s[e] = (_Float16)Wout[(size_t)wcol*64 + k];
        }
        woutf[kk] = s;
      }
    }
    float bov = boutg[ncol];
    float bb[4];
    #pragma unroll
    for (int g4 = 0; g4 < 4; ++g4) bb[g4] = b2v[g4*H2N + ncol];
    __syncthreads();
    int dlt = (lane >= 20 && lane < 32) ? 1 : BIGNEG;
    for (int t = 0; t < LSEQ; ++t) {
      unsigned short* xb = xh[t & 1];
      poll_all(cw, t + dlt);
      {
        const unsigned short* Bs = H1r + (size_t)(t & (D1 - 1)) * MR * H1P;
        const unsigned short* Cs = C2r + (size_t)((t + D2 - 1) & (D2 - 1)) * MR * 64;
        for (int idx = tid; idx < MR*24; idx += 256) {
          int r = idx/24, c8 = (idx%24)*8;
          *(u16x8*)(xb + (size_t)r*XH2S + c8) = ldg16_sc(Bs + (size_t)r*H1P + c8);
        }
        for (int idx = tid; idx < MR*8; idx += 256) {
          int r = idx >> 3, c8 = (idx & 7)*8;
          *(u16x8*)(xb + (size_t)r*XH2S + 192 + c8) = ldg16_sc(Cs + (size_t)r*64 + c8);
        }
      }
      __syncthreads();
      unsigned short* Cn = C2r + (size_t)(t & (D2 - 1)) * MR * 64;
      {
        f32x4 ac[4][2];
        #pragma unroll
        for (int g4 = 0; g4 < 4; ++g4) { ac[g4][0] = (f32x4){0,0,0,0}; ac[g4][1] = (f32x4){0,0,0,0}; }
        #pragma unroll
        for (int kk = 0; kk < KK2; ++kk) {
          f16x8 a0 = lda(xb, XH2S, 0, kk, lane);
          f16x8 a1 = lda(xb, XH2S, 1, kk, lane);
          #pragma unroll
          for (int g4 = 0; g4 < 4; ++g4) {
            ac[g4][0] = MFMA16(a0, wf[g4][kk], ac[g4][0]);
            ac[g4][1] = MFMA16(a1, wf[g4][kk], ac[g4][1]);
          }
        }
        #pragma unroll
        for (int m = 0; m < 2; ++m) {
          #pragma unroll
          for (int r = 0; r < 4; ++r) {
            float ff1 = ac[0][m][r] + bb[0];
            float ff2 = ac[1][m][r] + bb[1];
            float ta  = ac[2][m][r] + bb[2];
            float tb  = ac[3][m][r] + bb[3];
            float ti  = 1.f / (1.f + __expf(-(ta + tb)));
            float hv  = tanhf(ff1)*(1.f - ti) + ti*tanhf(ff2);
            stg_h_sc(&Cn[(size_t)(m*16 + (lane>>4)*4 + r)*64 + ncol], f2h_bits(hv));
          }
        }
        if (lane == 0) publish(&cnt[32 + tile], t + 1);
      }
      __syncthreads();   // all waves' c_t stores drained (barrier implies per-wave vmcnt drain)
      { // y_t = c_t @ Wout^T + bout ; wave = y col-tile, both m-tiles
        #pragma unroll
        for (int m = 0; m < 2; ++m) {
          f32x4 acc = {0.f,0.f,0.f,0.f};
          #pragma unroll
          for (int kk = 0; kk < 2; ++kk) {
            f16x8 a = __builtin_bit_cast(f16x8, ldg16_sc(Cn + (size_t)(m*16 + (lane & 15))*64 + kk*32 + ((lane >> 4) << 3)));
            acc = MFMA16(a, woutf[kk], acc);
          }
          int cc = lane & 15, rb = (lane >> 4) * 4;
          #pragma unroll
          for (int r = 0; r < 4; ++r) {
            int row = m*16 + rb + r;
            out[((size_t)(b0 + row) * LSEQ + t) * 64 + tile*16 + cc] = acc[r] + bov;
          }
        }
      }
    }
  }
}

extern "C" void kernel_launch(void* const* d_in, const int* in_sizes, int n_in,
                              void* d_out, int out_size, void* d_ws, size_t ws_size,
                              hipStream_t stream) {
  const float* dt   = (const float*)d_in[0];
  const float* hs   = (const float*)d_in[1];
  const float* W0   = (const float*)d_in[2];
  const float* b0v  = (const float*)d_in[3];
  const float* W1   = (const float*)d_in[4];
  const float* b1v  = (const float*)d_in[5];
  const float* W2   = (const float*)d_in[6];
  const float* b2v  = (const float*)d_in[7];
  const float* Wo   = (const float*)d_in[8];
  const float* bo   = (const float*)d_in[9];
  const float* M0   = (const float*)d_in[10];
  const float* M1   = (const float*)d_in[11];
  const float* M2   = (const float*)d_in[12];
  (void)in_sizes; (void)n_in; (void)out_size; (void)ws_size;
  init_state<<<16, 256, 0, stream>>>(hs, (char*)d_ws);
  // bid = j*16 + g : group g's 9 WGs share XCD (g%8) under round-robin dispatch
  rnn_persist<<<144, 256, 0, stream>>>(dt, W0, b0v, W1, b1v, W2, b2v, Wo, bo, M0, M1, M2,
                                       (float*)d_out, (char*)d_ws);
}

// Round 6
// 1524.765 us; speedup vs baseline: 1.1193x; 1.1193x over previous
//
#include <hip/hip_runtime.h>
#include <stdint.h>

typedef _Float16 f16x8 __attribute__((ext_vector_type(8)));
typedef unsigned short u16x8 __attribute__((ext_vector_type(8)));
typedef float f32x4 __attribute__((ext_vector_type(4)));

#define MFMA16(a,b,c) __builtin_amdgcn_mfma_f32_16x16x32_f16((a),(b),(c),0,0,0)

// problem dims
#define LSEQ 256
#define H0N  269
#define H1N  179
#define H0P  272
#define H1P  192
#define K0REAL 333
#define K1REAL 448
#define K2REAL 243
#define KK0  11    // K0 padded to 352
#define KK1  15    // [a:272|h1:192] padded to 480
#define KK2  8     // [b:192|c:64(hbuf)] = 256
#define XH0S 360
#define XH1S 488
#define XH2S 200
#define MR   32
#define D0   8
#define D1   8

// ws layout per group (bytes)
#define H0_OFF   0
#define H0_SLOT  (MR*H0P*2)            // 17408
#define H1_OFF   (D0*H0_SLOT)          // 139264
#define H1_SLOT  (MR*H1P*2)            // 12288
#define C2_OFF   (H1_OFF + D1*H1_SLOT) // 237568 (single init slot, 4KB)
#define CNT_OFF  (C2_OFF + 4096)
#define GSTRIDE  262144

#define BIGNEG   (-(1<<28))
#define NQ0 5
#define NQ1 8
#define NQ2 3

__device__ __forceinline__ unsigned short f2h_bits(float v) {
  return __builtin_bit_cast(unsigned short, (_Float16)v);
}
__device__ __forceinline__ float rcpf(float x) { return __builtin_amdgcn_rcpf(x); }
__device__ __forceinline__ float fast_sig(float s) { return rcpf(1.f + __expf(-s)); }
__device__ __forceinline__ float fast_tanh(float x) {
  float e = __expf(2.f * x);
  return 1.f - 2.f * rcpf(e + 1.f);
}

// ---- raw cache-bypass (coherent-at-MALL) memory ops; batched, non-atomic ----
__device__ __forceinline__ u16x8 ldg16_bp(const unsigned short* p) {
  u16x8 r;
  asm volatile("global_load_dwordx4 %0, %1, off sc0 sc1" : "=v"(r) : "v"(p));
  return r;
}
__device__ __forceinline__ void stg16_bp(unsigned short* p, u16x8 v) {
  asm volatile("global_store_dwordx4 %0, %1, off sc0 sc1" :: "v"(p), "v"(v) : "memory");
}
#define VM_WAIT0 do { asm volatile("s_waitcnt vmcnt(0)" ::: "memory"); __builtin_amdgcn_sched_barrier(0); } while (0)

// one-RTT parallel poll: lane i watches cnt[i]; exit when all lane conditions hold
__device__ __forceinline__ void poll_all(const unsigned int* cw, int tgt) {
  for (int it = 0; it < (1 << 17); ++it) {   // bounded: no hang on protocol bug
    unsigned int v;
    asm volatile("global_load_dword %0, %1, off sc0 sc1\n\ts_waitcnt vmcnt(0)"
                 : "=v"(v) : "v"(cw) : "memory");
    if (__all((int)v >= tgt)) return;
    __builtin_amdgcn_s_sleep(1);
  }
}
// publish: wave's prior bypass-stores drained, then flag store
__device__ __forceinline__ void publish(unsigned int* w, unsigned int v) {
  asm volatile("s_waitcnt vmcnt(0)" ::: "memory");
  asm volatile("global_store_dword %0, %1, off sc0 sc1" :: "v"(w), "v"(v) : "memory");
}

// ---------------- init: counters + t=-1 state slots ----------------
__global__ void __launch_bounds__(256) init_state(const float* __restrict__ hs, char* __restrict__ ws) {
  int g = blockIdx.x, tid = threadIdx.x;
  char* gb = ws + (size_t)g * GSTRIDE;
  if (tid < 64) ((unsigned int*)(gb + CNT_OFF))[tid] = 0u;
  int b0 = g * MR;
  unsigned short* H0 = (unsigned short*)(gb + H0_OFF + 7*(size_t)H0_SLOT);
  unsigned short* H1 = (unsigned short*)(gb + H1_OFF + 7*(size_t)H1_SLOT);
  unsigned short* C2 = (unsigned short*)(gb + C2_OFF);
  for (int i = tid; i < MR*H0P; i += 256) { int r = i/H0P, c = i%H0P; H0[i] = (c < H0N) ? f2h_bits(hs[(size_t)(b0+r)*512 + c]) : (unsigned short)0; }
  for (int i = tid; i < MR*H1P; i += 256) { int r = i/H1P, c = i%H1P; H1[i] = (c < H1N) ? f2h_bits(hs[(size_t)(b0+r)*512 + H0N + c]) : (unsigned short)0; }
  for (int i = tid; i < MR*64;  i += 256) { int r = i>>6,  c = i&63;  C2[i] = f2h_bits(hs[(size_t)(b0+r)*512 + 448 + c]); }
}

// ---------------- weight fragment builder (B operand, K x 16 tile) ----------------
template<int KK, int MODE>
__device__ __forceinline__ void build_frag(f16x8* wf, const float* __restrict__ W, const float* __restrict__ Msk,
                                           int h, int Kreal, int gate, int tile, int lane) {
  int col = tile * 16 + (lane & 15);
  bool nv = (col < h);
  #pragma unroll
  for (int kk = 0; kk < KK; ++kk) {
    f16x8 s;
    #pragma unroll
    for (int e = 0; e < 8; ++e) {
      int k = kk*32 + ((lane >> 4) << 3) + e;
      int wc;
      if (MODE == 0)      wc = (k < 333) ? k : -1;                                       // [x64|h269]
      else if (MODE == 1) wc = (k < 269) ? k : ((k >= 272 && k < 451) ? (k - 3) : -1);   // [a272|h1:179]
      else                wc = (k < 179) ? k : ((k >= 192 && k < 256) ? (k - 13) : -1);  // [b:179|c:64]
      float val = 0.f;
      if (nv && wc >= 0) {
        val = W[(size_t)(gate * h + col) * Kreal + wc];
        if (gate < 2) val *= Msk[(size_t)col * Kreal + wc];
      }
      s[e] = (_Float16)val;
    }
    wf[kk] = s;
  }
}

__device__ __forceinline__ f16x8 lda(const unsigned short* xh, int stride, int mt, int kk, int lane) {
  const unsigned short* p = xh + (size_t)(mt*16 + (lane & 15)) * stride + kk*32 + ((lane >> 4) << 3);
  return __builtin_bit_cast(f16x8, *(const u16x8*)p);
}

// ---------------- persistent cascade kernel ----------------
// 16 groups x 9 WGs (bid: g=bid&15, j=bid>>4 -> group's WGs share XCD g%8).
// j=0..4 cell0 (tile=j*4+wave, 17 active); j=5..7 cell1 (tile=(j-5)*4+wave);
// j=8 cell2+y (tile=wave; c-state lives in LDS hbuf, no global ring).
// cnt words: P0=[0..16], P1=[20..31], P2=[32..35]; P=t+1 when step-t stores visible.
// Poll (lane l watches cnt[l]): cell0: P0>=t, P1>=t-7(a-ring). cell1: P0>=t+1,
// P1>=t, P2>=t-7(b-ring). cell2: P1>=t+1. Acyclic in t -> deadlock-free.
__global__ void __launch_bounds__(256, 1) rnn_persist(
    const float* __restrict__ dt,
    const float* __restrict__ W0, const float* __restrict__ b0v,
    const float* __restrict__ W1, const float* __restrict__ b1v,
    const float* __restrict__ W2, const float* __restrict__ b2v,
    const float* __restrict__ Wout, const float* __restrict__ boutg,
    const float* __restrict__ M0, const float* __restrict__ M1, const float* __restrict__ M2,
    float* __restrict__ out, char* __restrict__ ws)
{
  __shared__ __attribute__((aligned(16))) unsigned short xhS[MR * XH1S];  // 31232 B
  __shared__ __attribute__((aligned(16))) unsigned short hbuf[4][32][16]; // 4 KB

  int tid = threadIdx.x;
  int lane = tid & 63, wave = tid >> 6;
  int bid = blockIdx.x;
  int j = bid >> 4;
  int g = bid & 15;
  int b0 = g * MR;

  char* gb = ws + (size_t)g * GSTRIDE;
  unsigned short* H0r = (unsigned short*)(gb + H0_OFF);
  unsigned short* H1r = (unsigned short*)(gb + H1_OFF);
  unsigned int*   cnt = (unsigned int*)(gb + CNT_OFF);
  const unsigned int* cw = cnt + lane;
  u16x8 zz = {0,0,0,0,0,0,0,0};

  if (j < 5) {
    // ================= cell0 =================
    int tile = j*4 + wave;
    bool act = (tile < 17);
    int ncol = tile*16 + (lane & 15);
    f16x8 wf[4][KK0];
    if (act) {
      #pragma unroll
      for (int g4 = 0; g4 < 4; ++g4) build_frag<KK0,0>(wf[g4], W0, M0, H0N, K0REAL, g4, tile, lane);
    }
    float bb[4] = {0.f,0.f,0.f,0.f};
    if (act && ncol < H0N) {
      for (int g4 = 0; g4 < 4; ++g4) bb[g4] = b0v[g4*H0N + ncol];
    }
    if (tid < 64) {  // static k-pad 336..351
      int r = tid >> 1, c8 = 336 + (tid & 1)*8;
      *(u16x8*)(xhS + (size_t)r*XH0S + c8) = zz;
    }
    // staging slots (constant across steps)
    int aoff[NQ0], adst[NQ0]; bool aval[NQ0];
    #pragma unroll
    for (int q = 0; q < NQ0; ++q) {
      int idx = tid + q*256;
      aval[q] = (idx < MR*34);
      int r = idx / 34, cc = (idx % 34) * 8;
      aoff[q] = r*H0P + cc;
      adst[q] = r*XH0S + 64 + cc;
    }
    int xrow = tid >> 3, xc = (tid & 7) * 8;
    const float* dtb = dt + ((size_t)(b0 + xrow) * LSEQ) * 64 + xc;
    float4 xA = *(const float4*)(dtb);
    float4 xB = *(const float4*)(dtb + 4);
    int dlt = (lane < 17) ? 0 : (lane >= 20 && lane < 32) ? -7 : BIGNEG;
    for (int t = 0; t < LSEQ; ++t) {
      { // write x(t) from prefetched regs
        unsigned short* d = xhS + (size_t)xrow*XH0S + xc;
        d[0]=f2h_bits(xA.x); d[1]=f2h_bits(xA.y); d[2]=f2h_bits(xA.z); d[3]=f2h_bits(xA.w);
        d[4]=f2h_bits(xB.x); d[5]=f2h_bits(xB.y); d[6]=f2h_bits(xB.z); d[7]=f2h_bits(xB.w);
      }
      poll_all(cw, t + dlt);
      { // batched bypass stage of a_{t-1}
        const unsigned short* H0s = H0r + (size_t)((t + 7) & 7) * (MR*H0P);
        u16x8 tA[NQ0];
        #pragma unroll
        for (int q = 0; q < NQ0; ++q) if (aval[q]) tA[q] = ldg16_bp(H0s + aoff[q]);
        VM_WAIT0;
        #pragma unroll
        for (int q = 0; q < NQ0; ++q) if (aval[q]) *(u16x8*)(xhS + adst[q]) = tA[q];
      }
      __syncthreads();                       // barA
      { int tn = (t + 1 < LSEQ) ? t + 1 : t; // prefetch x(t+1) under MFMA
        xA = *(const float4*)(dtb + (size_t)tn*64);
        xB = *(const float4*)(dtb + (size_t)tn*64 + 4); }
      f32x4 ac[4][2];
      if (act) {
        #pragma unroll
        for (int g4 = 0; g4 < 4; ++g4) { ac[g4][0] = (f32x4){0,0,0,0}; ac[g4][1] = (f32x4){0,0,0,0}; }
        #pragma unroll
        for (int kk = 0; kk < KK0; ++kk) {
          f16x8 a0 = lda(xhS, XH0S, 0, kk, lane);
          f16x8 a1 = lda(xhS, XH0S, 1, kk, lane);
          #pragma unroll
          for (int g4 = 0; g4 < 4; ++g4) {
            ac[g4][0] = MFMA16(a0, wf[g4][kk], ac[g4][0]);
            ac[g4][1] = MFMA16(a1, wf[g4][kk], ac[g4][1]);
          }
        }
      }
      __syncthreads();                       // barB (xh reads done)
      if (act) {
        #pragma unroll
        for (int m = 0; m < 2; ++m) {
          #pragma unroll
          for (int r = 0; r < 4; ++r) {
            float ti = fast_sig(ac[2][m][r] + bb[2] + ac[3][m][r] + bb[3]);
            float hv = fast_tanh(ac[0][m][r] + bb[0])*(1.f - ti) + ti*fast_tanh(ac[1][m][r] + bb[1]);
            hbuf[wave][m*16 + (lane>>4)*4 + r][lane & 15] = f2h_bits(hv);
          }
        }
        int row = lane >> 1, c8v = (lane & 1) * 8;
        u16x8 hv8 = *(const u16x8*)&hbuf[wave][row][c8v];
        unsigned short* Hn = H0r + (size_t)(t & 7) * (MR*H0P);
        stg16_bp(Hn + (size_t)row*H0P + tile*16 + c8v, hv8);
        if (lane == 0) publish(&cnt[tile], t + 1);
      }
    }
  } else if (j < 8) {
    // ================= cell1 =================
    int tile = (j - 5)*4 + wave;
    int ncol = tile*16 + (lane & 15);
    f16x8 wf[4][KK1];
    #pragma unroll
    for (int g4 = 0; g4 < 4; ++g4) build_frag<KK1,1>(wf[g4], W1, M1, H1N, K1REAL, g4, tile, lane);
    float bb[4] = {0.f,0.f,0.f,0.f};
    if (ncol < H1N) {
      for (int g4 = 0; g4 < 4; ++g4) bb[g4] = b1v[g4*H1N + ncol];
    }
    if (tid < 64) {  // static k-pad 464..479
      int r = tid >> 1, c8 = 464 + (tid & 1)*8;
      *(u16x8*)(xhS + (size_t)r*XH1S + c8) = zz;
    }
    int soff[NQ1], sdst[NQ1]; bool sval[NQ1], sisB[NQ1];
    #pragma unroll
    for (int q = 0; q < NQ1; ++q) {
      int idx = tid + q*256;
      if (idx < 1088) {
        sval[q] = true; sisB[q] = false;
        int r = idx / 34, cc = (idx % 34) * 8;
        soff[q] = r*H0P + cc; sdst[q] = r*XH1S + cc;
      } else {
        int i2 = idx - 1088;
        sval[q] = (i2 < 768); sisB[q] = true;
        int r = i2 / 24, cc = (i2 % 24) * 8;
        soff[q] = r*H1P + cc; sdst[q] = r*XH1S + 272 + cc;
      }
    }
    int dlt = (lane < 17) ? 1 : (lane >= 20 && lane < 32) ? 0 : (lane >= 32 && lane < 36) ? -7 : BIGNEG;
    for (int t = 0; t < LSEQ; ++t) {
      poll_all(cw, t + dlt);
      {
        const unsigned short* As = H0r + (size_t)(t & 7) * (MR*H0P);
        const unsigned short* Bs = H1r + (size_t)((t + 7) & 7) * (MR*H1P);
        u16x8 tS[NQ1];
        #pragma unroll
        for (int q = 0; q < NQ1; ++q) if (sval[q]) tS[q] = ldg16_bp((sisB[q] ? Bs : As) + soff[q]);
        VM_WAIT0;
        #pragma unroll
        for (int q = 0; q < NQ1; ++q) if (sval[q]) *(u16x8*)(xhS + sdst[q]) = tS[q];
      }
      __syncthreads();                       // barA
      f32x4 ac[4][2];
      #pragma unroll
      for (int g4 = 0; g4 < 4; ++g4) { ac[g4][0] = (f32x4){0,0,0,0}; ac[g4][1] = (f32x4){0,0,0,0}; }
      #pragma unroll
      for (int kk = 0; kk < KK1; ++kk) {
        f16x8 a0 = lda(xhS, XH1S, 0, kk, lane);
        f16x8 a1 = lda(xhS, XH1S, 1, kk, lane);
        #pragma unroll
        for (int g4 = 0; g4 < 4; ++g4) {
          ac[g4][0] = MFMA16(a0, wf[g4][kk], ac[g4][0]);
          ac[g4][1] = MFMA16(a1, wf[g4][kk], ac[g4][1]);
        }
      }
      __syncthreads();                       // barB
      {
        #pragma unroll
        for (int m = 0; m < 2; ++m) {
          #pragma unroll
          for (int r = 0; r < 4; ++r) {
            float ti = fast_sig(ac[2][m][r] + bb[2] + ac[3][m][r] + bb[3]);
            float hv = fast_tanh(ac[0][m][r] + bb[0])*(1.f - ti) + ti*fast_tanh(ac[1][m][r] + bb[1]);
            hbuf[wave][m*16 + (lane>>4)*4 + r][lane & 15] = f2h_bits(hv);
          }
        }
        int row = lane >> 1, c8v = (lane & 1) * 8;
        u16x8 hv8 = *(const u16x8*)&hbuf[wave][row][c8v];
        unsigned short* Hn = H1r + (size_t)(t & 7) * (MR*H1P);
        stg16_bp(Hn + (size_t)row*H1P + tile*16 + c8v, hv8);
        if (lane == 0) publish(&cnt[20 + tile], t + 1);
      }
    }
  } else {
    // ================= cell2 + y (c-state in hbuf; no global c ring) =================
    int tile = wave;
    int ncol = tile*16 + (lane & 15);
    f16x8 wf[4][KK2], woutf[2];
    #pragma unroll
    for (int g4 = 0; g4 < 4; ++g4) build_frag<KK2,2>(wf[g4], W2, M2, 64, K2REAL, g4, tile, lane);
    {
      #pragma unroll
      for (int kk = 0; kk < 2; ++kk) {
        f16x8 s;
        #pragma unroll
        for (int e = 0; e < 8; ++e) {
          int k = kk*32 + ((lane >> 4) << 3) + e;
          s[e] = (_Float16)Wout[(size_t)ncol*64 + k];
        }
        woutf[kk] = s;
      }
    }
    float bov = boutg[ncol];
    float bb[4];
    #pragma unroll
    for (int g4 = 0; g4 < 4; ++g4) bb[g4] = b2v[g4*64 + ncol];
    { // preload c_{-1} into hbuf
      const unsigned short* C2i = (const unsigned short*)(gb + C2_OFF);
      int r = tid >> 3, c8 = (tid & 7) * 8;
      u16x8 cv = ldg16_bp(C2i + r*64 + c8);
      VM_WAIT0;
      *(u16x8*)&hbuf[c8 >> 4][r][c8 & 15] = cv;
    }
    int soff[NQ2], sdst[NQ2];
    #pragma unroll
    for (int q = 0; q < NQ2; ++q) {
      int idx = tid + q*256;
      int r = idx / 24, cc = (idx % 24) * 8;
      soff[q] = r*H1P + cc; sdst[q] = r*XH2S + cc;
    }
    int dlt = (lane >= 20 && lane < 32) ? 1 : BIGNEG;
    for (int t = 0; t < LSEQ; ++t) {
      poll_all(cw, t + dlt);
      {
        const unsigned short* Bs = H1r + (size_t)(t & 7) * (MR*H1P);
        u16x8 tS[NQ2];
        #pragma unroll
        for (int q = 0; q < NQ2; ++q) tS[q] = ldg16_bp(Bs + soff[q]);
        VM_WAIT0;
        #pragma unroll
        for (int q = 0; q < NQ2; ++q) *(u16x8*)(xhS + sdst[q]) = tS[q];
      }
      __syncthreads();                       // barA (b_t staged; hbuf(t-1) intact)
      if (lane == 0) publish(&cnt[32 + wave], t + 1);   // b_t read complete
      f32x4 ac[4][2];
      #pragma unroll
      for (int g4 = 0; g4 < 4; ++g4) { ac[g4][0] = (f32x4){0,0,0,0}; ac[g4][1] = (f32x4){0,0,0,0}; }
      #pragma unroll
      for (int kk = 0; kk < KK2; ++kk) {
        f16x8 a0, a1;
        if (kk < 6) {
          a0 = lda(xhS, XH2S, 0, kk, lane);
          a1 = lda(xhS, XH2S, 1, kk, lane);
        } else {  // c-part from hbuf (c_{t-1})
          int k0 = kk*32 + ((lane >> 4) << 3) - 192;
          a0 = __builtin_bit_cast(f16x8, *(const u16x8*)&hbuf[k0 >> 4][(lane & 15)][k0 & 15]);
          a1 = __builtin_bit_cast(f16x8, *(const u16x8*)&hbuf[k0 >> 4][16 + (lane & 15)][k0 & 15]);
        }
        #pragma unroll
        for (int g4 = 0; g4 < 4; ++g4) {
          ac[g4][0] = MFMA16(a0, wf[g4][kk], ac[g4][0]);
          ac[g4][1] = MFMA16(a1, wf[g4][kk], ac[g4][1]);
        }
      }
      __syncthreads();                       // barB (hbuf c_{t-1} reads done)
      {
        #pragma unroll
        for (int m = 0; m < 2; ++m) {
          #pragma unroll
          for (int r = 0; r < 4; ++r) {
            float ti = fast_sig(ac[2][m][r] + bb[2] + ac[3][m][r] + bb[3]);
            float hv = fast_tanh(ac[0][m][r] + bb[0])*(1.f - ti) + ti*fast_tanh(ac[1][m][r] + bb[1]);
            hbuf[wave][m*16 + (lane>>4)*4 + r][lane & 15] = f2h_bits(hv);
          }
        }
      }
      __syncthreads();                       // barC (c_t complete in hbuf)
      { // y_t = c_t @ Wout^T + bout (A from hbuf)
        #pragma unroll
        for (int m = 0; m < 2; ++m) {
          f32x4 acc = {0.f,0.f,0.f,0.f};
          #pragma unroll
          for (int kk = 0; kk < 2; ++kk) {
            int k0 = kk*32 + ((lane >> 4) << 3);
            f16x8 a = __builtin_bit_cast(f16x8, *(const u16x8*)&hbuf[k0 >> 4][m*16 + (lane & 15)][k0 & 15]);
            acc = MFMA16(a, woutf[kk], acc);
          }
          int cc = lane & 15, rb = (lane >> 4) * 4;
          #pragma unroll
          for (int r = 0; r < 4; ++r) {
            int row = m*16 + rb + r;
            out[((size_t)(b0 + row) * LSEQ + t) * 64 + tile*16 + cc] = acc[r] + bov;
          }
        }
      }
    }
  }
}

extern "C" void kernel_launch(void* const* d_in, const int* in_sizes, int n_in,
                              void* d_out, int out_size, void* d_ws, size_t ws_size,
                              hipStream_t stream) {
  const float* dt   = (const float*)d_in[0];
  const float* hs   = (const float*)d_in[1];
  const float* W0   = (const float*)d_in[2];
  const float* b0v  = (const float*)d_in[3];
  const float* W1   = (const float*)d_in[4];
  const float* b1v  = (const float*)d_in[5];
  const float* W2   = (const float*)d_in[6];
  const float* b2v  = (const float*)d_in[7];
  const float* Wo   = (const float*)d_in[8];
  const float* bo   = (const float*)d_in[9];
  const float* M0   = (const float*)d_in[10];
  const float* M1   = (const float*)d_in[11];
  const float* M2   = (const float*)d_in[12];
  (void)in_sizes; (void)n_in; (void)out_size; (void)ws_size;
  init_state<<<16, 256, 0, stream>>>(hs, (char*)d_ws);
  rnn_persist<<<144, 256, 0, stream>>>(dt, W0, b0v, W1, b1v, W2, b2v, Wo, bo, M0, M1, M2,
                                       (float*)d_out, (char*)d_ws);
}

// Round 9
// 1064.348 us; speedup vs baseline: 1.6035x; 1.4326x over previous
//
#include <hip/hip_runtime.h>
#include <stdint.h>

typedef _Float16 f16x8 __attribute__((ext_vector_type(8)));
typedef unsigned short u16x8 __attribute__((ext_vector_type(8)));
typedef float f32x4 __attribute__((ext_vector_type(4)));
typedef unsigned int u32x4 __attribute__((ext_vector_type(4)));

#define MFMA16(a,b,c) __builtin_amdgcn_mfma_f32_16x16x32_f16((a),(b),(c),0,0,0)

// problem dims
#define LSEQ 256
#define H0N  269
#define H1N  179
#define H0P  272
#define H1P  192
#define K0REAL 333
#define K1REAL 448
#define K2REAL 243
#define KK0  11    // K0 padded to 352
#define KK1  15    // [a:272|h1:192] padded to 480
#define KK2  8     // [b:192|c:64(hbuf)] = 256
#define XH0S 360
#define XH1S 488
#define XH2S 200
#define MR   32

// ws layout per group (bytes)
#define H0_OFF   0
#define H0_SLOT  (MR*H0P*2)            // 17408
#define H1_OFF   (8*H0_SLOT)           // 139264
#define H1_SLOT  (MR*H1P*2)            // 12288
#define C2_OFF   (H1_OFF + 8*H1_SLOT)  // 237568 (c_{-1} init slot)
#define CNT_OFF  (C2_OFF + 4096)       // 9 ring-guard words
#define GSTRIDE  262144

#define BIGNEG   (-(1<<28))
#define NQ0 5
#define NQ1 8
#define NQ2 3

__device__ __forceinline__ unsigned short f2h_bits(float v) {
  return __builtin_bit_cast(unsigned short, (_Float16)v);
}
__device__ __forceinline__ float rcpf(float x) { return __builtin_amdgcn_rcpf(x); }
__device__ __forceinline__ float fast_sig(float s) { return rcpf(1.f + __expf(-s)); }
__device__ __forceinline__ float fast_tanh(float x) {
  float e = __expf(2.f * x);
  return 1.f - 2.f * rcpf(e + 1.f);
}

// ---- MALL-coherent (sc0 sc1) ops — the only HW-proven cross-WG path ----
__device__ __forceinline__ u16x8 ldg16s(const unsigned short* p) {
  u16x8 r;
  asm volatile("global_load_dwordx4 %0, %1, off sc0 sc1" : "=v"(r) : "v"(p));
  return r;
}
__device__ __forceinline__ void stg16s(unsigned short* p, u16x8 v) {
  asm volatile("global_store_dwordx4 %0, %1, off sc0 sc1" :: "v"(p), "v"(v) : "memory");
}
__device__ __forceinline__ unsigned ld_flag(const unsigned int* p) {
  unsigned v;
  asm volatile("global_load_dword %0, %1, off sc0 sc1" : "=v"(v) : "v"(p) : "memory");
  return v;
}
__device__ __forceinline__ void st_flag(unsigned int* p, unsigned v) {
  asm volatile("global_store_dword %0, %1, off sc0 sc1" :: "v"(p), "v"(v) : "memory");
}
#define VM_WAIT0 do { asm volatile("s_waitcnt vmcnt(0)" ::: "memory"); __builtin_amdgcn_sched_barrier(0); } while (0)

// ---- step tags in fp16 mantissa bit0: tagf(s) = ((s+8)>>3)&1 (flips per ring lap) ----
__device__ __forceinline__ bool chunk_fresh(u16x8 v, unsigned tp) {
  u32x4 d = __builtin_bit_cast(u32x4, v);
  return ((d[0] & 0x00010001u) == tp) & ((d[1] & 0x00010001u) == tp) &
         ((d[2] & 0x00010001u) == tp) & ((d[3] & 0x00010001u) == tp);
}
__device__ __forceinline__ u16x8 tag_chunk(u16x8 v, unsigned tp) {
  u32x4 d = __builtin_bit_cast(u32x4, v);
  d &= 0xFFFEFFFEu;
  d |= tp;
  return __builtin_bit_cast(u16x8, d);
}

// ---------------- init: scrub rings to tag-0, write t=-1 state (tag 0) ----------------
__global__ void __launch_bounds__(256) init_state(const float* __restrict__ hs, char* __restrict__ ws) {
  int g = blockIdx.x, tid = threadIdx.x;
  char* gb = ws + (size_t)g * GSTRIDE;
  uint4 z4 = {0,0,0,0};
  int total16 = (CNT_OFF + 512) / 16;
  for (int i = tid; i < total16; i += 256) ((uint4*)gb)[i] = z4;   // rings zeroed -> tag 0
  __syncthreads();
  int b0 = g * MR;
  unsigned short* H0 = (unsigned short*)(gb + H0_OFF + 7*(size_t)H0_SLOT);
  unsigned short* H1 = (unsigned short*)(gb + H1_OFF + 7*(size_t)H1_SLOT);
  unsigned short* C2 = (unsigned short*)(gb + C2_OFF);
  for (int i = tid; i < MR*H0P; i += 256) { int r = i/H0P, c = i%H0P;
    H0[i] = (c < H0N) ? (unsigned short)(f2h_bits(hs[(size_t)(b0+r)*512 + c]) & 0xFFFEu) : (unsigned short)0; }
  for (int i = tid; i < MR*H1P; i += 256) { int r = i/H1P, c = i%H1P;
    H1[i] = (c < H1N) ? (unsigned short)(f2h_bits(hs[(size_t)(b0+r)*512 + H0N + c]) & 0xFFFEu) : (unsigned short)0; }
  for (int i = tid; i < MR*64;  i += 256) { int r = i>>6,  c = i&63;
    C2[i] = f2h_bits(hs[(size_t)(b0+r)*512 + 448 + c]); }
}

// ---------------- weight fragment builder, 3 gates (gate2 = W_ta + W_tb) ----------------
template<int KK, int MODE>
__device__ __forceinline__ void build_frag3(f16x8* wf, const float* __restrict__ W, const float* __restrict__ Msk,
                                            int h, int Kreal, int g4, int tile, int lane) {
  int col = tile * 16 + (lane & 15);
  bool nv = (col < h);
  #pragma unroll
  for (int kk = 0; kk < KK; ++kk) {
    f16x8 s;
    #pragma unroll
    for (int e = 0; e < 8; ++e) {
      int k = kk*32 + ((lane >> 4) << 3) + e;
      int wc;
      if (MODE == 0)      wc = (k < 333) ? k : -1;
      else if (MODE == 1) wc = (k < 269) ? k : ((k >= 272 && k < 451) ? (k - 3) : -1);
      else                wc = (k < 179) ? k : ((k >= 192 && k < 256) ? (k - 13) : -1);
      float val = 0.f;
      if (nv && wc >= 0) {
        if (g4 < 2) val = W[(size_t)(g4 * h + col) * Kreal + wc] * Msk[(size_t)col * Kreal + wc];
        else        val = W[(size_t)(2 * h + col) * Kreal + wc] + W[(size_t)(3 * h + col) * Kreal + wc];
      }
      s[e] = (_Float16)val;
    }
    wf[kk] = s;
  }
}

__device__ __forceinline__ f16x8 lda(const unsigned short* xh, int stride, int mt, int kk, int lane) {
  const unsigned short* p = xh + (size_t)(mt*16 + (lane & 15)) * stride + kk*32 + ((lane >> 4) << 3);
  return __builtin_bit_cast(f16x8, *(const u16x8*)p);
}

// ---------------- persistent cascade kernel ----------------
// 16 groups x 9 WGs. j=0..4 cell0 (tile=j*4+wave, 17 active waves);
// j=5..7 cell1; j=8 cell2+y (c in LDS).
// Sync: data-as-flag (mantissa-bit0 step tags) for readiness; cnt[0..8] are
// ring-reuse guard counters ONLY (cnt[wg]=t+1 after staging step t, 6-7 slack).
// Overwrite guards guarantee a slot is never retagged while a reader polls it.
__global__ void __launch_bounds__(256, 1) rnn_persist(
    const float* __restrict__ dt,
    const float* __restrict__ W0, const float* __restrict__ b0v,
    const float* __restrict__ W1, const float* __restrict__ b1v,
    const float* __restrict__ W2, const float* __restrict__ b2v,
    const float* __restrict__ Wout, const float* __restrict__ boutg,
    const float* __restrict__ M0, const float* __restrict__ M1, const float* __restrict__ M2,
    float* __restrict__ out, char* __restrict__ ws)
{
  __shared__ __attribute__((aligned(16))) unsigned short xhS[MR * XH1S];  // 31232 B
  __shared__ __attribute__((aligned(16))) unsigned short hbuf[4][32][16]; // 4 KB

  int tid = threadIdx.x;
  int lane = tid & 63, wave = tid >> 6;
  int bid = blockIdx.x;
  int j = bid >> 4;
  int g = bid & 15;
  int b0 = g * MR;

  char* gb = ws + (size_t)g * GSTRIDE;
  unsigned short* H0r = (unsigned short*)(gb + H0_OFF);
  unsigned short* H1r = (unsigned short*)(gb + H1_OFF);
  unsigned int*   cnt = (unsigned int*)(gb + CNT_OFF);
  u16x8 zz = {0,0,0,0,0,0,0,0};

  if (j < 5) {
    // ================= cell0 =================
    int tile = j*4 + wave;
    bool act = (tile < 17);
    int ncol = tile*16 + (lane & 15);
    bool cok = act && (ncol < H0N);
    f16x8 wf[3][KK0];
    if (act) {
      #pragma unroll
      for (int g4 = 0; g4 < 3; ++g4) build_frag3<KK0,0>(wf[g4], W0, M0, H0N, K0REAL, g4, tile, lane);
    }
    float bb[3] = {0.f,0.f,0.f};
    if (cok) {
      bb[0] = b0v[ncol]; bb[1] = b0v[H0N + ncol];
      bb[2] = b0v[2*H0N + ncol] + b0v[3*H0N + ncol];
    }
    if (tid < 64) {  // static k-pad 336..351
      int r = tid >> 1, c8 = 336 + (tid & 1)*8;
      *(u16x8*)(xhS + (size_t)r*XH0S + c8) = zz;
    }
    int aoff[NQ0], adst[NQ0]; bool aval[NQ0];
    #pragma unroll
    for (int q = 0; q < NQ0; ++q) {
      int idx = tid + q*256;
      aval[q] = (idx < MR*34);
      int r = idx / 34, cc = (idx % 34) * 8;
      aoff[q] = r*H0P + cc;
      adst[q] = r*XH0S + 64 + cc;
    }
    int xrow = tid >> 3, xc = (tid & 7) * 8;
    const float* dtb = dt + ((size_t)(b0 + xrow) * LSEQ) * 64 + xc;
    float4 xA = *(const float4*)(dtb);
    float4 xB = *(const float4*)(dtb + 4);
    int goff = (lane < 5) ? -6 : (lane < 8) ? -7 : BIGNEG;   // a-ring guards
    for (int t = 0; t < LSEQ; ++t) {
      unsigned tpm1 = (((unsigned)(t + 7) >> 3) & 1) * 0x00010001u;  // tag of a_{t-1}
      unsigned tpt  = (((unsigned)(t + 8) >> 3) & 1) * 0x00010001u;  // tag of a_t
      { // write x_t from prefetched regs
        unsigned short* d = xhS + (size_t)xrow*XH0S + xc;
        d[0]=f2h_bits(xA.x); d[1]=f2h_bits(xA.y); d[2]=f2h_bits(xA.z); d[3]=f2h_bits(xA.w);
        d[4]=f2h_bits(xB.x); d[5]=f2h_bits(xB.y); d[6]=f2h_bits(xB.z); d[7]=f2h_bits(xB.w);
      }
      // tag-poll a_{t-1} (the poll IS the read) + ring guards
      const unsigned short* H0s = H0r + (size_t)((t + 7) & 7) * (MR*H0P);
      u16x8 tA[NQ0];
      for (int it = 0; it < (1 << 17); ++it) {
        unsigned gv = 0;
        if (lane < 8) gv = ld_flag(cnt + lane);
        #pragma unroll
        for (int q = 0; q < NQ0; ++q) if (aval[q]) tA[q] = ldg16s(H0s + aoff[q]);
        VM_WAIT0;
        bool ok = ((int)gv >= t + goff);
        #pragma unroll
        for (int q = 0; q < NQ0; ++q) if (aval[q]) ok &= chunk_fresh(tA[q], tpm1);
        if (__all(ok)) break;
        __builtin_amdgcn_s_sleep(1);
      }
      #pragma unroll
      for (int q = 0; q < NQ0; ++q) if (aval[q]) *(u16x8*)(xhS + adst[q]) = tA[q];
      __syncthreads();                       // barA
      if (tid == 0) st_flag(&cnt[j], t + 1); // staged -> release a-ring slot
      { int tn = (t + 1 < LSEQ) ? t + 1 : t; // prefetch x(t+1) under MFMA
        xA = *(const float4*)(dtb + (size_t)tn*64);
        xB = *(const float4*)(dtb + (size_t)tn*64 + 4); }
      f32x4 ac[3][2];
      if (act) {
        #pragma unroll
        for (int g4 = 0; g4 < 3; ++g4) { ac[g4][0] = (f32x4){0,0,0,0}; ac[g4][1] = (f32x4){0,0,0,0}; }
        #pragma unroll
        for (int kk = 0; kk < KK0; ++kk) {
          f16x8 a0 = lda(xhS, XH0S, 0, kk, lane);
          f16x8 a1 = lda(xhS, XH0S, 1, kk, lane);
          #pragma unroll
          for (int g4 = 0; g4 < 3; ++g4) {
            ac[g4][0] = MFMA16(a0, wf[g4][kk], ac[g4][0]);
            ac[g4][1] = MFMA16(a1, wf[g4][kk], ac[g4][1]);
          }
        }
      }
      __syncthreads();                       // barB (xhS reads done)
      if (act) {
        #pragma unroll
        for (int m = 0; m < 2; ++m) {
          #pragma unroll
          for (int r = 0; r < 4; ++r) {
            float ti = fast_sig(ac[2][m][r] + bb[2]);
            float hv = cok ? (fast_tanh(ac[0][m][r] + bb[0])*(1.f - ti) + ti*fast_tanh(ac[1][m][r] + bb[1])) : 0.f;
            hbuf[wave][m*16 + (lane>>4)*4 + r][lane & 15] = f2h_bits(hv);
          }
        }
        int row = lane >> 1, c8v = (lane & 1) * 8;
        u16x8 hv8 = tag_chunk(*(const u16x8*)&hbuf[wave][row][c8v], tpt);
        unsigned short* Hn = H0r + (size_t)(t & 7) * (MR*H0P);
        stg16s(Hn + (size_t)row*H0P + tile*16 + c8v, hv8);   // tagged store IS the flag
      }
    }
  } else if (j < 8) {
    // ================= cell1 =================
    int tile = (j - 5)*4 + wave;
    int ncol = tile*16 + (lane & 15);
    bool cok = (ncol < H1N);
    f16x8 wf[3][KK1];
    #pragma unroll
    for (int g4 = 0; g4 < 3; ++g4) build_frag3<KK1,1>(wf[g4], W1, M1, H1N, K1REAL, g4, tile, lane);
    float bb[3] = {0.f,0.f,0.f};
    if (cok) {
      bb[0] = b1v[ncol]; bb[1] = b1v[H1N + ncol];
      bb[2] = b1v[2*H1N + ncol] + b1v[3*H1N + ncol];
    }
    if (tid < 64) {  // static k-pad 464..479
      int r = tid >> 1, c8 = 464 + (tid & 1)*8;
      *(u16x8*)(xhS + (size_t)r*XH1S + c8) = zz;
    }
    int soff[NQ1], sdst[NQ1]; bool sval[NQ1], sisB[NQ1];
    #pragma unroll
    for (int q = 0; q < NQ1; ++q) {
      int idx = tid + q*256;
      if (idx < 1088) {
        sval[q] = true; sisB[q] = false;
        int r = idx / 34, cc = (idx % 34) * 8;
        soff[q] = r*H0P + cc; sdst[q] = r*XH1S + cc;
      } else {
        int i2 = idx - 1088;
        sval[q] = (i2 < 768); sisB[q] = true;
        int r = i2 / 24, cc = (i2 % 24) * 8;
        soff[q] = r*H1P + cc; sdst[q] = r*XH1S + 272 + cc;
      }
    }
    int goff = (lane >= 5 && lane < 8) ? -6 : (lane == 8) ? -7 : BIGNEG;  // b-ring guards
    for (int t = 0; t < LSEQ; ++t) {
      unsigned tpm1 = (((unsigned)(t + 7) >> 3) & 1) * 0x00010001u;  // b_{t-1}
      unsigned tpt  = (((unsigned)(t + 8) >> 3) & 1) * 0x00010001u;  // a_t / b_t
      const unsigned short* As = H0r + (size_t)(t & 7) * (MR*H0P);
      const unsigned short* Bs = H1r + (size_t)((t + 7) & 7) * (MR*H1P);
      u16x8 tS[NQ1];
      for (int it = 0; it < (1 << 17); ++it) {
        unsigned gv = 0;
        if (lane >= 5 && lane < 9) gv = ld_flag(cnt + lane);
        #pragma unroll
        for (int q = 0; q < NQ1; ++q) if (sval[q]) tS[q] = ldg16s((sisB[q] ? Bs : As) + soff[q]);
        VM_WAIT0;
        bool ok = ((int)gv >= t + goff);
        #pragma unroll
        for (int q = 0; q < NQ1; ++q) if (sval[q]) ok &= chunk_fresh(tS[q], sisB[q] ? tpm1 : tpt);
        if (__all(ok)) break;
        __builtin_amdgcn_s_sleep(1);
      }
      #pragma unroll
      for (int q = 0; q < NQ1; ++q) if (sval[q]) *(u16x8*)(xhS + sdst[q]) = tS[q];
      __syncthreads();                       // barA
      if (tid == 0) st_flag(&cnt[j], t + 1);
      f32x4 ac[3][2];
      #pragma unroll
      for (int g4 = 0; g4 < 3; ++g4) { ac[g4][0] = (f32x4){0,0,0,0}; ac[g4][1] = (f32x4){0,0,0,0}; }
      #pragma unroll
      for (int kk = 0; kk < KK1; ++kk) {
        f16x8 a0 = lda(xhS, XH1S, 0, kk, lane);
        f16x8 a1 = lda(xhS, XH1S, 1, kk, lane);
        #pragma unroll
        for (int g4 = 0; g4 < 3; ++g4) {
          ac[g4][0] = MFMA16(a0, wf[g4][kk], ac[g4][0]);
          ac[g4][1] = MFMA16(a1, wf[g4][kk], ac[g4][1]);
        }
      }
      __syncthreads();                       // barB
      {
        #pragma unroll
        for (int m = 0; m < 2; ++m) {
          #pragma unroll
          for (int r = 0; r < 4; ++r) {
            float ti = fast_sig(ac[2][m][r] + bb[2]);
            float hv = cok ? (fast_tanh(ac[0][m][r] + bb[0])*(1.f - ti) + ti*fast_tanh(ac[1][m][r] + bb[1])) : 0.f;
            hbuf[wave][m*16 + (lane>>4)*4 + r][lane & 15] = f2h_bits(hv);
          }
        }
        int row = lane >> 1, c8v = (lane & 1) * 8;
        u16x8 hv8 = tag_chunk(*(const u16x8*)&hbuf[wave][row][c8v], tpt);
        unsigned short* Hn = H1r + (size_t)(t & 7) * (MR*H1P);
        stg16s(Hn + (size_t)row*H1P + tile*16 + c8v, hv8);
      }
    }
  } else {
    // ================= cell2 + y (c-state in hbuf; no global ring, no guards) =================
    int tile = wave;
    int ncol = tile*16 + (lane & 15);
    f16x8 wf[3][KK2], woutf[2];
    #pragma unroll
    for (int g4 = 0; g4 < 3; ++g4) build_frag3<KK2,2>(wf[g4], W2, M2, 64, K2REAL, g4, tile, lane);
    {
      #pragma unroll
      for (int kk = 0; kk < 2; ++kk) {
        f16x8 s;
        #pragma unroll
        for (int e = 0; e < 8; ++e) {
          int k = kk*32 + ((lane >> 4) << 3) + e;
          s[e] = (_Float16)Wout[(size_t)ncol*64 + k];
        }
        woutf[kk] = s;
      }
    }
    float bov = boutg[ncol];
    float bb[3];
    bb[0] = b2v[ncol]; bb[1] = b2v[64 + ncol];
    bb[2] = b2v[2*64 + ncol] + b2v[3*64 + ncol];
    { // preload c_{-1}
      const unsigned short* C2i = (const unsigned short*)(gb + C2_OFF);
      int r = tid >> 3, c8 = (tid & 7) * 8;
      u16x8 cv = ldg16s(C2i + r*64 + c8);
      VM_WAIT0;
      *(u16x8*)&hbuf[c8 >> 4][r][c8 & 15] = cv;
    }
    int soff[NQ2], sdst[NQ2];
    #pragma unroll
    for (int q = 0; q < NQ2; ++q) {
      int idx = tid + q*256;
      int r = idx / 24, cc = (idx % 24) * 8;
      soff[q] = r*H1P + cc; sdst[q] = r*XH2S + cc;
    }
    for (int t = 0; t < LSEQ; ++t) {
      unsigned tpt = (((unsigned)(t + 8) >> 3) & 1) * 0x00010001u;  // b_t
      const unsigned short* Bs = H1r + (size_t)(t & 7) * (MR*H1P);
      u16x8 tS[NQ2];
      for (int it = 0; it < (1 << 17); ++it) {
        #pragma unroll
        for (int q = 0; q < NQ2; ++q) tS[q] = ldg16s(Bs + soff[q]);
        VM_WAIT0;
        bool ok = true;
        #pragma unroll
        for (int q = 0; q < NQ2; ++q) ok &= chunk_fresh(tS[q], tpt);
        if (__all(ok)) break;
        __builtin_amdgcn_s_sleep(1);
      }
      #pragma unroll
      for (int q = 0; q < NQ2; ++q) *(u16x8*)(xhS + sdst[q]) = tS[q];
      __syncthreads();                       // barA
      if (tid == 0) st_flag(&cnt[8], t + 1); // b_t consumed -> release b-ring slot
      f32x4 ac[3][2];
      #pragma unroll
      for (int g4 = 0; g4 < 3; ++g4) { ac[g4][0] = (f32x4){0,0,0,0}; ac[g4][1] = (f32x4){0,0,0,0}; }
      #pragma unroll
      for (int kk = 0; kk < KK2; ++kk) {
        f16x8 a0, a1;
        if (kk < 6) {
          a0 = lda(xhS, XH2S, 0, kk, lane);
          a1 = lda(xhS, XH2S, 1, kk, lane);
        } else {  // c_{t-1} from hbuf
          int k0 = kk*32 + ((lane >> 4) << 3) - 192;
          a0 = __builtin_bit_cast(f16x8, *(const u16x8*)&hbuf[k0 >> 4][(lane & 15)][k0 & 15]);
          a1 = __builtin_bit_cast(f16x8, *(const u16x8*)&hbuf[k0 >> 4][16 + (lane & 15)][k0 & 15]);
        }
        #pragma unroll
        for (int g4 = 0; g4 < 3; ++g4) {
          ac[g4][0] = MFMA16(a0, wf[g4][kk], ac[g4][0]);
          ac[g4][1] = MFMA16(a1, wf[g4][kk], ac[g4][1]);
        }
      }
      __syncthreads();                       // barB (hbuf c_{t-1} reads done)
      {
        #pragma unroll
        for (int m = 0; m < 2; ++m) {
          #pragma unroll
          for (int r = 0; r < 4; ++r) {
            float ti = fast_sig(ac[2][m][r] + bb[2]);
            float hv = fast_tanh(ac[0][m][r] + bb[0])*(1.f - ti) + ti*fast_tanh(ac[1][m][r] + bb[1]);
            hbuf[wave][m*16 + (lane>>4)*4 + r][lane & 15] = f2h_bits(hv);
          }
        }
      }
      __syncthreads();                       // barC (c_t complete in hbuf)
      { // y_t = c_t @ Wout^T + bout
        #pragma unroll
        for (int m = 0; m < 2; ++m) {
          f32x4 acc = {0.f,0.f,0.f,0.f};
          #pragma unroll
          for (int kk = 0; kk < 2; ++kk) {
            int k0 = kk*32 + ((lane >> 4) << 3);
            f16x8 a = __builtin_bit_cast(f16x8, *(const u16x8*)&hbuf[k0 >> 4][m*16 + (lane & 15)][k0 & 15]);
            acc = MFMA16(a, woutf[kk], acc);
          }
          int cc = lane & 15, rb = (lane >> 4) * 4;
          #pragma unroll
          for (int r = 0; r < 4; ++r) {
            int row = m*16 + rb + r;
            out[((size_t)(b0 + row) * LSEQ + t) * 64 + tile*16 + cc] = acc[r] + bov;
          }
        }
      }
    }
  }
}

extern "C" void kernel_launch(void* const* d_in, const int* in_sizes, int n_in,
                              void* d_out, int out_size, void* d_ws, size_t ws_size,
                              hipStream_t stream) {
  const float* dt   = (const float*)d_in[0];
  const float* hs   = (const float*)d_in[1];
  const float* W0   = (const float*)d_in[2];
  const float* b0v  = (const float*)d_in[3];
  const float* W1   = (const float*)d_in[4];
  const float* b1v  = (const float*)d_in[5];
  const float* W2   = (const float*)d_in[6];
  const float* b2v  = (const float*)d_in[7];
  const float* Wo   = (const float*)d_in[8];
  const float* bo   = (const float*)d_in[9];
  const float* M0   = (const float*)d_in[10];
  const float* M1   = (const float*)d_in[11];
  const float* M2   = (const float*)d_in[12];
  (void)in_sizes; (void)n_in; (void)out_size; (void)ws_size;
  init_state<<<16, 256, 0, stream>>>(hs, (char*)d_ws);
  rnn_persist<<<144, 256, 0, stream>>>(dt, W0, b0v, W1, b1v, W2, b2v, Wo, bo, M0, M1, M2,
                                       (float*)d_out, (char*)d_ws);
}